// Round 4
// baseline (361.992 us; speedup 1.0000x reference)
//
#include <hip/hip_runtime.h>
#include <stdint.h>

#define BB   8
#define NN   2048
#define FIN  256
#define FOUT 128

using short8 = __attribute__((ext_vector_type(8))) short;
using f32x4  = __attribute__((ext_vector_type(4))) float;

__device__ __forceinline__ unsigned short rbf(float f) {
    return (unsigned short)((__float_as_uint(f) + 0x8000u) >> 16);
}

// Calibration: 2 probe MFMAs read off the true (row,col) label of each
// accumulator element (validated round 4). Epilogues index by these labels.
__device__ __forceinline__ void mfma_calib(int m, int quad, int* Mlab, int* Nlab) {
    short8 pa1, pb1, pa2, pb2;
    const short one = (short)0x3F80;            // bf16 1.0
    const short mb  = (short)rbf((float)m);     // bf16 m (exact, m<16)
#pragma unroll
    for (int j = 0; j < 8; ++j) { pa1[j] = 0; pa2[j] = 0; pb1[j] = mb; pb2[j] = one; }
    if (quad == 0) { pa1[0] = one; pa2[0] = mb; }
    f32x4 zz = {0.f, 0.f, 0.f, 0.f};
    f32x4 c1 = __builtin_amdgcn_mfma_f32_16x16x32_bf16(pa1, pb1, zz, 0, 0, 0);
    f32x4 c2 = __builtin_amdgcn_mfma_f32_16x16x32_bf16(pa2, pb2, zz, 0, 0, 0);
#pragma unroll
    for (int r = 0; r < 4; ++r) {
        Nlab[r] = ((int)c1[r]) & 15;
        Mlab[r] = ((int)c2[r]) & 15;
    }
}

// ---------------- W[256][128] fp32 -> wt[128][256] bf16 (W^T) --------------
__global__ __launch_bounds__(256) void gat_wt(const float* __restrict__ W,
                                              unsigned short* __restrict__ wt) {
    const int g  = blockIdx.x * 256 + threadIdx.x;
    const int k  = g >> 5;
    const int o4 = (g & 31) << 2;
    float4 wv = *(const float4*)(W + (k << 7) + o4);
    wt[((o4 + 0) << 8) + k] = rbf(wv.x);
    wt[((o4 + 1) << 8) + k] = rbf(wv.y);
    wt[((o4 + 2) << 8) + k] = rbf(wv.z);
    wt[((o4 + 3) << 8) + k] = rbf(wv.w);
}

// ---------------- stage 1: h = x@W via MFMA (16 rows/block, 1024 blocks) ---
__global__ __launch_bounds__(256) void gat_h3(
        const float* __restrict__ x, const unsigned short* __restrict__ wt,
        const float* __restrict__ a, unsigned short* __restrict__ ht,
        float* __restrict__ f1, float* __restrict__ f2) {
    __shared__ unsigned short xs[16][264];
    __shared__ float hs[16][132];
    const int bk   = blockIdx.x;
    const int R0   = bk << 4;
    const int b    = R0 >> 11;
    const int il0  = R0 & (NN - 1);
    const int tid  = threadIdx.x;
    const int w    = tid >> 6;
    const int lane = tid & 63;
    const int m    = lane & 15;
    const int quad = lane >> 4;

#pragma unroll
    for (int rr = 0; rr < 4; ++rr) {
        const int row = (w << 2) + rr;
        float4 xv = *(const float4*)(x + (size_t)(R0 + row) * FIN + (lane << 2));
        ushort4 c4;
        c4.x = rbf(xv.x); c4.y = rbf(xv.y); c4.z = rbf(xv.z); c4.w = rbf(xv.w);
        *(ushort4*)(&xs[row][lane << 2]) = c4;
    }
    int Mlab[4], Nlab[4];
    mfma_calib(m, quad, Mlab, Nlab);
    __syncthreads();

    f32x4 zz = {0.f, 0.f, 0.f, 0.f};
    f32x4 acc[2] = {zz, zz};
#pragma unroll
    for (int kc = 0; kc < 8; ++kc) {
        const int k0 = (kc << 5) + (quad << 3);
        short8 av = *(const short8*)(&xs[m][k0]);
#pragma unroll
        for (int t = 0; t < 2; ++t) {
            const int ot = (w << 1) + t;
            short8 bw = *(const short8*)(wt + (((ot << 4) + m) << 8) + k0);
            acc[t] = __builtin_amdgcn_mfma_f32_16x16x32_bf16(av, bw, acc[t], 0, 0, 0);
        }
    }
#pragma unroll
    for (int t = 0; t < 2; ++t)
#pragma unroll
        for (int r = 0; r < 4; ++r)
            hs[Mlab[r]][(((w << 1) + t) << 4) + Nlab[r]] = acc[t][r];
    __syncthreads();

    {
        const int i   = tid >> 4;
        const int seg = tid & 15;
        const int o0  = seg << 3;
        float s1 = 0.f, s2 = 0.f;
#pragma unroll
        for (int e = 0; e < 8; ++e) {
            float hv = hs[i][o0 + e];
            s1 = fmaf(hv, a[o0 + e], s1);
            s2 = fmaf(hv, a[FOUT + o0 + e], s2);
        }
        s1 += __shfl_xor(s1, 1); s1 += __shfl_xor(s1, 2);
        s1 += __shfl_xor(s1, 4); s1 += __shfl_xor(s1, 8);
        s2 += __shfl_xor(s2, 1); s2 += __shfl_xor(s2, 2);
        s2 += __shfl_xor(s2, 4); s2 += __shfl_xor(s2, 8);
        if (seg == 0) { f1[R0 + i] = s1; f2[R0 + i] = s2; }
    }
    {
        const int o  = tid >> 1;
        const int i8 = (tid & 1) << 3;
        short8 hv;
#pragma unroll
        for (int e = 0; e < 8; ++e) hv[e] = (short)rbf(hs[i8 + e][o]);
        *(short8*)(ht + ((size_t)((b << 7) + o) << 11) + il0 + i8) = hv;
    }
}

// ---------------- stage 2a: fused masked-softmax attention, j-split=2 ------
// R4: R0's gat_s4 loop (2 P-fragments/wave, intensity preserved) with the
// j range split across 2 blocks. Grid 512 -> 1024 = 4 blocks/CU x 4 waves
// = 16 waves/CU (2x R0). Per-chunk traffic, total adj bytes and total ht
// L2 bytes identical to R0 (R3's i-split halved intensity -> regressed).
// Blocks write raw half-partials + denominator partials to workspace
// (disjoint, no atomics); gat_fin normalizes.
__global__ __launch_bounds__(256, 4) void gat_s2a(
        const int* __restrict__ adj, const unsigned short* __restrict__ ht,
        const float* __restrict__ f1, const float* __restrict__ f2,
        float* __restrict__ wsp, float* __restrict__ wss) {
    const int bk   = blockIdx.x;        // 0..1023
    const int b    = bk & 7;            // batch fastest -> per-XCD L2 locality
    const int jh   = (bk >> 3) & 1;     // j-half
    const int i0   = (bk >> 4) << 5;    // 32 rows per tile
    const int tid  = threadIdx.x;
    const int w    = tid >> 6;          // j-quarter within the half
    const int lane = tid & 63;
    const int m    = lane & 15;
    const int quad = lane >> 4;

    __shared__ float accb[2][32][128];  // 32 KB
    __shared__ float sbuf[4][2][16];

    int Mlab[4], Nlab[4];
    mfma_calib(m, quad, Mlab, Nlab);

    const int gi0 = (b << 11) + i0;
    const float f1a = f1[gi0 + m];
    const float f1b = f1[gi0 + 16 + m];
    const int* adjr0 = adj + ((size_t)(gi0 + m) << 11);
    const int* adjr1 = adj + ((size_t)(gi0 + 16 + m) << 11);
    const float* f2b = f2 + (b << 11);
    const unsigned short* htb = ht + ((size_t)b << 18);

    f32x4 zz = {0.f, 0.f, 0.f, 0.f};
    f32x4 acc1[8], acc2[8];
#pragma unroll
    for (int t = 0; t < 8; ++t) { acc1[t] = zz; acc2[t] = zz; }
    float s1 = 0.f, s2 = 0.f;

    const int jb = (jh << 10) + (w << 8) + (quad << 3);
#pragma unroll 2
    for (int c = 0; c < 8; ++c) {
        const int j0 = jb + (c << 5);
        short8 hf[8];
#pragma unroll
        for (int ot = 0; ot < 8; ++ot)
            hf[ot] = *(const short8*)(htb + ((size_t)((ot << 4) + m) << 11) + j0);

        int4   aA0 = *(const int4*)(adjr0 + j0);
        int4   aA1 = *(const int4*)(adjr0 + j0 + 4);
        int4   aB0 = *(const int4*)(adjr1 + j0);
        int4   aB1 = *(const int4*)(adjr1 + j0 + 4);
        float4 fa  = *(const float4*)(f2b + j0);
        float4 fb  = *(const float4*)(f2b + j0 + 4);
        float fm[8] = {fa.x, fa.y, fa.z, fa.w, fb.x, fb.y, fb.z, fb.w};

        float pA[8], pB[8];
        {
            int am[8] = {aA0.x, aA0.y, aA0.z, aA0.w, aA1.x, aA1.y, aA1.z, aA1.w};
#pragma unroll
            for (int u = 0; u < 8; ++u) {
                float e = f1a + fm[u];
                pA[u] = (am[u] > 0) ? __expf(fmaxf(e, 0.2f * e)) : 0.f;
            }
        }
        {
            int bm[8] = {aB0.x, aB0.y, aB0.z, aB0.w, aB1.x, aB1.y, aB1.z, aB1.w};
#pragma unroll
            for (int u = 0; u < 8; ++u) {
                float e = f1b + fm[u];
                pB[u] = (bm[u] > 0) ? __expf(fmaxf(e, 0.2f * e)) : 0.f;
            }
        }
        s1 += ((pA[0] + pA[1]) + (pA[2] + pA[3])) + ((pA[4] + pA[5]) + (pA[6] + pA[7]));
        s2 += ((pB[0] + pB[1]) + (pB[2] + pB[3])) + ((pB[4] + pB[5]) + (pB[6] + pB[7]));

        short8 pf1, pf2;
#pragma unroll
        for (int u = 0; u < 8; ++u) { pf1[u] = (short)rbf(pA[u]); pf2[u] = (short)rbf(pB[u]); }

#pragma unroll
        for (int ot = 0; ot < 8; ++ot) {
            acc1[ot] = __builtin_amdgcn_mfma_f32_16x16x32_bf16(pf1, hf[ot], acc1[ot], 0, 0, 0);
            acc2[ot] = __builtin_amdgcn_mfma_f32_16x16x32_bf16(pf2, hf[ot], acc2[ot], 0, 0, 0);
        }
    }

    // per-row denominator partials (quad-reduce within wave)
    s1 += __shfl_xor(s1, 16); s1 += __shfl_xor(s1, 32);
    s2 += __shfl_xor(s2, 16); s2 += __shfl_xor(s2, 32);
    if (lane < 16) { sbuf[w][0][lane] = s1; sbuf[w][1][lane] = s2; }

    // 2-phase accumulator combine (R0 skeleton): waves 0,1 write; 2,3 add.
    if (w < 2) {
#pragma unroll
        for (int ot = 0; ot < 8; ++ot)
#pragma unroll
            for (int r = 0; r < 4; ++r) {
                accb[w][Mlab[r]][(ot << 4) + Nlab[r]]      = acc1[ot][r];
                accb[w][16 + Mlab[r]][(ot << 4) + Nlab[r]] = acc2[ot][r];
            }
    }
    __syncthreads();
    if (w >= 2) {
#pragma unroll
        for (int ot = 0; ot < 8; ++ot)
#pragma unroll
            for (int r = 0; r < 4; ++r) {
                accb[w - 2][Mlab[r]][(ot << 4) + Nlab[r]]      += acc1[ot][r];
                accb[w - 2][16 + Mlab[r]][(ot << 4) + Nlab[r]] += acc2[ot][r];
            }
    }
    __syncthreads();

    // write raw half-partials + denominators to workspace (no norm here)
    {
        const int row = tid >> 3;           // 0..31
        const int o0  = (tid & 7) << 4;     // 16 floats per thread
        float* prow = wsp + ((size_t)jh << 21) + (((size_t)gi0 + row) << 7) + o0;
#pragma unroll
        for (int v4 = 0; v4 < 4; ++v4) {
            float4 rv;
            rv.x = accb[0][row][o0 + 4 * v4 + 0] + accb[1][row][o0 + 4 * v4 + 0];
            rv.y = accb[0][row][o0 + 4 * v4 + 1] + accb[1][row][o0 + 4 * v4 + 1];
            rv.z = accb[0][row][o0 + 4 * v4 + 2] + accb[1][row][o0 + 4 * v4 + 2];
            rv.w = accb[0][row][o0 + 4 * v4 + 3] + accb[1][row][o0 + 4 * v4 + 3];
            *(float4*)(prow + 4 * v4) = rv;
        }
    }
    if (tid < 32) {
        const int g  = tid >> 4;
        const int mm = tid & 15;
        const float s = (sbuf[0][g][mm] + sbuf[1][g][mm]) +
                        (sbuf[2][g][mm] + sbuf[3][g][mm]);
        wss[(jh << 14) + gi0 + tid] = s;
    }
}

// ---------------- stage 2b: combine halves + normalize + ELU ---------------
__global__ __launch_bounds__(256) void gat_fin(
        const float* __restrict__ wsp, const float* __restrict__ wss,
        float* __restrict__ out) {
    const int g4 = blockIdx.x * 256 + threadIdx.x;   // 0..524287
    const int gi = g4 >> 5;                          // global row
    const float s   = wss[gi] + wss[(1 << 14) + gi];
    const float inv = 1.0f / s;
    float4 p0 = *(const float4*)(wsp + ((size_t)g4 << 2));
    float4 p1 = *(const float4*)(wsp + (1u << 21) + ((size_t)g4 << 2));
    float4 rv;
    float y;
    y = (p0.x + p1.x) * inv; rv.x = y > 0.f ? y : expm1f(y);
    y = (p0.y + p1.y) * inv; rv.y = y > 0.f ? y : expm1f(y);
    y = (p0.z + p1.z) * inv; rv.z = y > 0.f ? y : expm1f(y);
    y = (p0.w + p1.w) * inv; rv.w = y > 0.f ? y : expm1f(y);
    *(float4*)(out + ((size_t)g4 << 2)) = rv;
}

extern "C" void kernel_launch(void* const* d_in, const int* in_sizes, int n_in,
                              void* d_out, int out_size, void* d_ws, size_t ws_size,
                              hipStream_t stream) {
    const float* x   = nullptr;
    const int*   adj = nullptr;
    const float* W   = nullptr;
    const float* a   = nullptr;
    for (int i = 0; i < n_in; ++i) {
        const long s = in_sizes[i];
        if      (s == (long)BB * NN * NN)  adj = (const int*)d_in[i];
        else if (s == (long)BB * NN * FIN) x   = (const float*)d_in[i];
        else if (s == (long)FIN * FOUT)    W   = (const float*)d_in[i];
        else if (s == 2L * FOUT)           a   = (const float*)d_in[i];
    }
    if (!x)   x   = (const float*)d_in[0];
    if (!adj) adj = (const int*)d_in[1];
    if (!W)   W   = (const float*)d_in[2];
    if (!a)   a   = (const float*)d_in[3];
    float* out = (float*)d_out;

    unsigned short* wt = (unsigned short*)d_ws;            // 64 KB   W^T bf16
    unsigned short* ht = wt + 32768;                       // 4 MB    h^T bf16 [B][128][N]
    float* f1  = (float*)(ht + (size_t)BB * NN * FOUT);    // 64 KB
    float* f2  = f1 + BB * NN;                             // 64 KB
    float* wss = f2 + BB * NN;                             // 128 KB  denom partials [2][16384]
    float* wsp = wss + 2 * BB * NN;                        // 16 MB   acc partials [2][16384][128]

    hipLaunchKernelGGL(gat_wt,  dim3(32),   dim3(256), 0, stream, W, wt);
    hipLaunchKernelGGL(gat_h3,  dim3(1024), dim3(256), 0, stream, x, wt, a, ht, f1, f2);
    hipLaunchKernelGGL(gat_s2a, dim3(1024), dim3(256), 0, stream, adj, ht, f1, f2, wsp, wss);
    hipLaunchKernelGGL(gat_fin, dim3(2048), dim3(256), 0, stream, wsp, wss, out);
}

// Round 5
// 267.189 us; speedup vs baseline: 1.3548x; 1.3548x over previous
//
#include <hip/hip_runtime.h>
#include <stdint.h>

#define BB   8
#define NN   2048
#define FIN  256
#define FOUT 128

using short8 = __attribute__((ext_vector_type(8))) short;
using f32x4  = __attribute__((ext_vector_type(4))) float;

__device__ __forceinline__ unsigned short rbf(float f) {
    return (unsigned short)((__float_as_uint(f) + 0x8000u) >> 16);
}

// Calibration: 2 probe MFMAs read off the true (row,col) label of each
// accumulator element (validated round 4). Epilogues index by these labels.
__device__ __forceinline__ void mfma_calib(int m, int quad, int* Mlab, int* Nlab) {
    short8 pa1, pb1, pa2, pb2;
    const short one = (short)0x3F80;            // bf16 1.0
    const short mb  = (short)rbf((float)m);     // bf16 m (exact, m<16)
#pragma unroll
    for (int j = 0; j < 8; ++j) { pa1[j] = 0; pa2[j] = 0; pb1[j] = mb; pb2[j] = one; }
    if (quad == 0) { pa1[0] = one; pa2[0] = mb; }
    f32x4 zz = {0.f, 0.f, 0.f, 0.f};
    f32x4 c1 = __builtin_amdgcn_mfma_f32_16x16x32_bf16(pa1, pb1, zz, 0, 0, 0);
    f32x4 c2 = __builtin_amdgcn_mfma_f32_16x16x32_bf16(pa2, pb2, zz, 0, 0, 0);
#pragma unroll
    for (int r = 0; r < 4; ++r) {
        Nlab[r] = ((int)c1[r]) & 15;
        Mlab[r] = ((int)c2[r]) & 15;
    }
}

// ---------------- W[256][128] fp32 -> wt[128][256] bf16 (W^T) --------------
__global__ __launch_bounds__(256) void gat_wt(const float* __restrict__ W,
                                              unsigned short* __restrict__ wt) {
    const int g  = blockIdx.x * 256 + threadIdx.x;
    const int k  = g >> 5;
    const int o4 = (g & 31) << 2;
    float4 wv = *(const float4*)(W + (k << 7) + o4);
    wt[((o4 + 0) << 8) + k] = rbf(wv.x);
    wt[((o4 + 1) << 8) + k] = rbf(wv.y);
    wt[((o4 + 2) << 8) + k] = rbf(wv.z);
    wt[((o4 + 3) << 8) + k] = rbf(wv.w);
}

// ---------------- adj[16384][2048] int32 -> bm[16384][256] bitmask ---------
// Streaming compress: 134 MB -> 4.2 MB (525 KB/batch = L2-resident/XCD).
// One block per row; thread packs 8 elems -> 1 byte (bit u <=> adj[..8t+u]>0).
__global__ __launch_bounds__(256) void gat_bm(const int* __restrict__ adj,
                                              unsigned char* __restrict__ bm) {
    const int row = blockIdx.x;                 // 0..16383
    const int tid = threadIdx.x;
    const int4* p = (const int4*)(adj + ((size_t)row << 11) + (tid << 3));
    int4 a0 = p[0];
    int4 a1 = p[1];
    unsigned int b = (unsigned int)(a0.x > 0)
                   | ((unsigned int)(a0.y > 0) << 1)
                   | ((unsigned int)(a0.z > 0) << 2)
                   | ((unsigned int)(a0.w > 0) << 3)
                   | ((unsigned int)(a1.x > 0) << 4)
                   | ((unsigned int)(a1.y > 0) << 5)
                   | ((unsigned int)(a1.z > 0) << 6)
                   | ((unsigned int)(a1.w > 0) << 7);
    bm[(row << 8) + tid] = (unsigned char)b;
}

// ---------------- stage 1: h = x@W via MFMA (16 rows/block, 1024 blocks) ---
__global__ __launch_bounds__(256) void gat_h3(
        const float* __restrict__ x, const unsigned short* __restrict__ wt,
        const float* __restrict__ a, unsigned short* __restrict__ ht,
        float* __restrict__ f1, float* __restrict__ f2) {
    __shared__ unsigned short xs[16][264];
    __shared__ float hs[16][132];
    const int bk   = blockIdx.x;
    const int R0   = bk << 4;
    const int b    = R0 >> 11;
    const int il0  = R0 & (NN - 1);
    const int tid  = threadIdx.x;
    const int w    = tid >> 6;
    const int lane = tid & 63;
    const int m    = lane & 15;
    const int quad = lane >> 4;

#pragma unroll
    for (int rr = 0; rr < 4; ++rr) {
        const int row = (w << 2) + rr;
        float4 xv = *(const float4*)(x + (size_t)(R0 + row) * FIN + (lane << 2));
        ushort4 c4;
        c4.x = rbf(xv.x); c4.y = rbf(xv.y); c4.z = rbf(xv.z); c4.w = rbf(xv.w);
        *(ushort4*)(&xs[row][lane << 2]) = c4;
    }
    int Mlab[4], Nlab[4];
    mfma_calib(m, quad, Mlab, Nlab);
    __syncthreads();

    f32x4 zz = {0.f, 0.f, 0.f, 0.f};
    f32x4 acc[2] = {zz, zz};
#pragma unroll
    for (int kc = 0; kc < 8; ++kc) {
        const int k0 = (kc << 5) + (quad << 3);
        short8 av = *(const short8*)(&xs[m][k0]);
#pragma unroll
        for (int t = 0; t < 2; ++t) {
            const int ot = (w << 1) + t;
            short8 bw = *(const short8*)(wt + (((ot << 4) + m) << 8) + k0);
            acc[t] = __builtin_amdgcn_mfma_f32_16x16x32_bf16(av, bw, acc[t], 0, 0, 0);
        }
    }
#pragma unroll
    for (int t = 0; t < 2; ++t)
#pragma unroll
        for (int r = 0; r < 4; ++r)
            hs[Mlab[r]][(((w << 1) + t) << 4) + Nlab[r]] = acc[t][r];
    __syncthreads();

    {
        const int i   = tid >> 4;
        const int seg = tid & 15;
        const int o0  = seg << 3;
        float s1 = 0.f, s2 = 0.f;
#pragma unroll
        for (int e = 0; e < 8; ++e) {
            float hv = hs[i][o0 + e];
            s1 = fmaf(hv, a[o0 + e], s1);
            s2 = fmaf(hv, a[FOUT + o0 + e], s2);
        }
        s1 += __shfl_xor(s1, 1); s1 += __shfl_xor(s1, 2);
        s1 += __shfl_xor(s1, 4); s1 += __shfl_xor(s1, 8);
        s2 += __shfl_xor(s2, 1); s2 += __shfl_xor(s2, 2);
        s2 += __shfl_xor(s2, 4); s2 += __shfl_xor(s2, 8);
        if (seg == 0) { f1[R0 + i] = s1; f2[R0 + i] = s2; }
    }
    {
        const int o  = tid >> 1;
        const int i8 = (tid & 1) << 3;
        short8 hv;
#pragma unroll
        for (int e = 0; e < 8; ++e) hv[e] = (short)rbf(hs[i8 + e][o]);
        *(short8*)(ht + ((size_t)((b << 7) + o) << 11) + il0 + i8) = hv;
    }
}

// ---------------- stage 2a: fused masked-softmax attention, j-split=2 ------
// R5: R4 loop with (a) adj int4 loads -> 1-byte bitmask loads (L2-resident,
// HBM stream eliminated), (b) launch_bounds(256,2): unified-reg cap 256 so
// the 2-fragment loop (92 VGPR + 64 AGPR = ~156) CANNOT spill (R1/R4 failure
// mode: cap 128 - 64 AGPR left 64 arch regs -> 300MB scratch). Occupancy is
// then register-limited at 3 blocks/CU = 12 waves/CU with grid 1024.
__global__ __launch_bounds__(256, 2) void gat_s2b(
        const unsigned char* __restrict__ bm, const unsigned short* __restrict__ ht,
        const float* __restrict__ f1, const float* __restrict__ f2,
        float* __restrict__ wsp, float* __restrict__ wss) {
    const int bk   = blockIdx.x;        // 0..1023
    const int b    = bk & 7;            // batch fastest -> per-XCD L2 locality
    const int jh   = (bk >> 3) & 1;     // j-half
    const int i0   = (bk >> 4) << 5;    // 32 rows per tile
    const int tid  = threadIdx.x;
    const int w    = tid >> 6;          // j-quarter within the half
    const int lane = tid & 63;
    const int m    = lane & 15;
    const int quad = lane >> 4;

    __shared__ float accb[2][32][128];  // 32 KB
    __shared__ float sbuf[4][2][16];

    int Mlab[4], Nlab[4];
    mfma_calib(m, quad, Mlab, Nlab);

    const int gi0 = (b << 11) + i0;
    const float f1a = f1[gi0 + m];
    const float f1b = f1[gi0 + 16 + m];
    const unsigned char* bmr0 = bm + ((size_t)(gi0 + m) << 8);
    const unsigned char* bmr1 = bm + ((size_t)(gi0 + 16 + m) << 8);
    const int mb0 = (jh << 7) + (w << 5) + quad;   // mask byte base within row
    const float* f2b = f2 + (b << 11);
    const unsigned short* htb = ht + ((size_t)b << 18);

    f32x4 zz = {0.f, 0.f, 0.f, 0.f};
    f32x4 acc1[8], acc2[8];
#pragma unroll
    for (int t = 0; t < 8; ++t) { acc1[t] = zz; acc2[t] = zz; }
    float s1 = 0.f, s2 = 0.f;

    const int jb = (jh << 10) + (w << 8) + (quad << 3);
#pragma unroll 2
    for (int c = 0; c < 8; ++c) {
        const int j0 = jb + (c << 5);
        short8 hf[8];
#pragma unroll
        for (int ot = 0; ot < 8; ++ot)
            hf[ot] = *(const short8*)(htb + ((size_t)((ot << 4) + m) << 11) + j0);

        const unsigned int mA = bmr0[mb0 + (c << 2)];
        const unsigned int mB = bmr1[mb0 + (c << 2)];
        float4 fa  = *(const float4*)(f2b + j0);
        float4 fb  = *(const float4*)(f2b + j0 + 4);
        float fm[8] = {fa.x, fa.y, fa.z, fa.w, fb.x, fb.y, fb.z, fb.w};

        float pA[8], pB[8];
#pragma unroll
        for (int u = 0; u < 8; ++u) {
            float e = f1a + fm[u];
            pA[u] = (mA & (1u << u)) ? __expf(fmaxf(e, 0.2f * e)) : 0.f;
        }
#pragma unroll
        for (int u = 0; u < 8; ++u) {
            float e = f1b + fm[u];
            pB[u] = (mB & (1u << u)) ? __expf(fmaxf(e, 0.2f * e)) : 0.f;
        }
        s1 += ((pA[0] + pA[1]) + (pA[2] + pA[3])) + ((pA[4] + pA[5]) + (pA[6] + pA[7]));
        s2 += ((pB[0] + pB[1]) + (pB[2] + pB[3])) + ((pB[4] + pB[5]) + (pB[6] + pB[7]));

        short8 pf1, pf2;
#pragma unroll
        for (int u = 0; u < 8; ++u) { pf1[u] = (short)rbf(pA[u]); pf2[u] = (short)rbf(pB[u]); }

#pragma unroll
        for (int ot = 0; ot < 8; ++ot) {
            acc1[ot] = __builtin_amdgcn_mfma_f32_16x16x32_bf16(pf1, hf[ot], acc1[ot], 0, 0, 0);
            acc2[ot] = __builtin_amdgcn_mfma_f32_16x16x32_bf16(pf2, hf[ot], acc2[ot], 0, 0, 0);
        }
    }

    // per-row denominator partials (quad-reduce within wave)
    s1 += __shfl_xor(s1, 16); s1 += __shfl_xor(s1, 32);
    s2 += __shfl_xor(s2, 16); s2 += __shfl_xor(s2, 32);
    if (lane < 16) { sbuf[w][0][lane] = s1; sbuf[w][1][lane] = s2; }

    // 2-phase accumulator combine (R0 skeleton): waves 0,1 write; 2,3 add.
    if (w < 2) {
#pragma unroll
        for (int ot = 0; ot < 8; ++ot)
#pragma unroll
            for (int r = 0; r < 4; ++r) {
                accb[w][Mlab[r]][(ot << 4) + Nlab[r]]      = acc1[ot][r];
                accb[w][16 + Mlab[r]][(ot << 4) + Nlab[r]] = acc2[ot][r];
            }
    }
    __syncthreads();
    if (w >= 2) {
#pragma unroll
        for (int ot = 0; ot < 8; ++ot)
#pragma unroll
            for (int r = 0; r < 4; ++r) {
                accb[w - 2][Mlab[r]][(ot << 4) + Nlab[r]]      += acc1[ot][r];
                accb[w - 2][16 + Mlab[r]][(ot << 4) + Nlab[r]] += acc2[ot][r];
            }
    }
    __syncthreads();

    // write raw half-partials + denominators to workspace (no norm here)
    {
        const int row = tid >> 3;           // 0..31
        const int o0  = (tid & 7) << 4;     // 16 floats per thread
        float* prow = wsp + ((size_t)jh << 21) + (((size_t)gi0 + row) << 7) + o0;
#pragma unroll
        for (int v4 = 0; v4 < 4; ++v4) {
            float4 rv;
            rv.x = accb[0][row][o0 + 4 * v4 + 0] + accb[1][row][o0 + 4 * v4 + 0];
            rv.y = accb[0][row][o0 + 4 * v4 + 1] + accb[1][row][o0 + 4 * v4 + 1];
            rv.z = accb[0][row][o0 + 4 * v4 + 2] + accb[1][row][o0 + 4 * v4 + 2];
            rv.w = accb[0][row][o0 + 4 * v4 + 3] + accb[1][row][o0 + 4 * v4 + 3];
            *(float4*)(prow + 4 * v4) = rv;
        }
    }
    if (tid < 32) {
        const int g  = tid >> 4;
        const int mm = tid & 15;
        const float s = (sbuf[0][g][mm] + sbuf[1][g][mm]) +
                        (sbuf[2][g][mm] + sbuf[3][g][mm]);
        wss[(jh << 14) + gi0 + tid] = s;
    }
}

// ---------------- stage 2b: combine halves + normalize + ELU ---------------
__global__ __launch_bounds__(256) void gat_fin(
        const float* __restrict__ wsp, const float* __restrict__ wss,
        float* __restrict__ out) {
    const int g4 = blockIdx.x * 256 + threadIdx.x;   // 0..524287
    const int gi = g4 >> 5;                          // global row
    const float s   = wss[gi] + wss[(1 << 14) + gi];
    const float inv = 1.0f / s;
    float4 p0 = *(const float4*)(wsp + ((size_t)g4 << 2));
    float4 p1 = *(const float4*)(wsp + (1u << 21) + ((size_t)g4 << 2));
    float4 rv;
    float y;
    y = (p0.x + p1.x) * inv; rv.x = y > 0.f ? y : expm1f(y);
    y = (p0.y + p1.y) * inv; rv.y = y > 0.f ? y : expm1f(y);
    y = (p0.z + p1.z) * inv; rv.z = y > 0.f ? y : expm1f(y);
    y = (p0.w + p1.w) * inv; rv.w = y > 0.f ? y : expm1f(y);
    *(float4*)(out + ((size_t)g4 << 2)) = rv;
}

extern "C" void kernel_launch(void* const* d_in, const int* in_sizes, int n_in,
                              void* d_out, int out_size, void* d_ws, size_t ws_size,
                              hipStream_t stream) {
    const float* x   = nullptr;
    const int*   adj = nullptr;
    const float* W   = nullptr;
    const float* a   = nullptr;
    for (int i = 0; i < n_in; ++i) {
        const long s = in_sizes[i];
        if      (s == (long)BB * NN * NN)  adj = (const int*)d_in[i];
        else if (s == (long)BB * NN * FIN) x   = (const float*)d_in[i];
        else if (s == (long)FIN * FOUT)    W   = (const float*)d_in[i];
        else if (s == 2L * FOUT)           a   = (const float*)d_in[i];
    }
    if (!x)   x   = (const float*)d_in[0];
    if (!adj) adj = (const int*)d_in[1];
    if (!W)   W   = (const float*)d_in[2];
    if (!a)   a   = (const float*)d_in[3];
    float* out = (float*)d_out;

    unsigned short* wt = (unsigned short*)d_ws;            // 64 KB   W^T bf16
    unsigned short* ht = wt + 32768;                       // 4 MB    h^T bf16 [B][128][N]
    float* f1  = (float*)(ht + (size_t)BB * NN * FOUT);    // 64 KB
    float* f2  = f1 + BB * NN;                             // 64 KB
    float* wss = f2 + BB * NN;                             // 128 KB  denom partials [2][16384]
    float* wsp = wss + 2 * BB * NN;                        // 16 MB   acc partials [2][16384][128]
    unsigned char* bmw = (unsigned char*)(wsp + 2 * (size_t)BB * NN * FOUT); // 4 MB bitmask

    hipLaunchKernelGGL(gat_wt,  dim3(32),    dim3(256), 0, stream, W, wt);
    hipLaunchKernelGGL(gat_bm,  dim3(16384), dim3(256), 0, stream, adj, bmw);
    hipLaunchKernelGGL(gat_h3,  dim3(1024),  dim3(256), 0, stream, x, wt, a, ht, f1, f2);
    hipLaunchKernelGGL(gat_s2b, dim3(1024),  dim3(256), 0, stream, bmw, ht, f1, f2, wsp, wss);
    hipLaunchKernelGGL(gat_fin, dim3(2048),  dim3(256), 0, stream, wsp, wss, out);
}

// Round 7
// 261.621 us; speedup vs baseline: 1.3837x; 1.0213x over previous
//
#include <hip/hip_runtime.h>
#include <stdint.h>

#define BB   8
#define NN   2048
#define FIN  256
#define FOUT 128

using short8 = __attribute__((ext_vector_type(8))) short;
using f32x4  = __attribute__((ext_vector_type(4))) float;

__device__ __forceinline__ unsigned short rbf(float f) {
    return (unsigned short)((__float_as_uint(f) + 0x8000u) >> 16);
}

// Calibration: 2 probe MFMAs read off the true (row,col) label of each
// accumulator element (validated round 4). Epilogues index by these labels.
__device__ __forceinline__ void mfma_calib(int m, int quad, int* Mlab, int* Nlab) {
    short8 pa1, pb1, pa2, pb2;
    const short one = (short)0x3F80;            // bf16 1.0
    const short mb  = (short)rbf((float)m);     // bf16 m (exact, m<16)
#pragma unroll
    for (int j = 0; j < 8; ++j) { pa1[j] = 0; pa2[j] = 0; pb1[j] = mb; pb2[j] = one; }
    if (quad == 0) { pa1[0] = one; pa2[0] = mb; }
    f32x4 zz = {0.f, 0.f, 0.f, 0.f};
    f32x4 c1 = __builtin_amdgcn_mfma_f32_16x16x32_bf16(pa1, pb1, zz, 0, 0, 0);
    f32x4 c2 = __builtin_amdgcn_mfma_f32_16x16x32_bf16(pa2, pb2, zz, 0, 0, 0);
#pragma unroll
    for (int r = 0; r < 4; ++r) {
        Nlab[r] = ((int)c1[r]) & 15;
        Mlab[r] = ((int)c2[r]) & 15;
    }
}

// ---------------- W[256][128] fp32 -> wt[128][256] bf16 (W^T) --------------
__global__ __launch_bounds__(256) void gat_wt(const float* __restrict__ W,
                                              unsigned short* __restrict__ wt) {
    const int g  = blockIdx.x * 256 + threadIdx.x;
    const int k  = g >> 5;
    const int o4 = (g & 31) << 2;
    float4 wv = *(const float4*)(W + (k << 7) + o4);
    wt[((o4 + 0) << 8) + k] = rbf(wv.x);
    wt[((o4 + 1) << 8) + k] = rbf(wv.y);
    wt[((o4 + 2) << 8) + k] = rbf(wv.z);
    wt[((o4 + 3) << 8) + k] = rbf(wv.w);
}

// ---------------- adj[16384][2048] int32 -> bm[16384][256] bitmask ---------
// Streaming compress: 134 MB -> 4.2 MB (525 KB/batch = L2-resident/XCD).
__global__ __launch_bounds__(256) void gat_bm(const int* __restrict__ adj,
                                              unsigned char* __restrict__ bm) {
    const int row = blockIdx.x;                 // 0..16383
    const int tid = threadIdx.x;
    const int4* p = (const int4*)(adj + ((size_t)row << 11) + (tid << 3));
    int4 a0 = p[0];
    int4 a1 = p[1];
    unsigned int b = (unsigned int)(a0.x > 0)
                   | ((unsigned int)(a0.y > 0) << 1)
                   | ((unsigned int)(a0.z > 0) << 2)
                   | ((unsigned int)(a0.w > 0) << 3)
                   | ((unsigned int)(a1.x > 0) << 4)
                   | ((unsigned int)(a1.y > 0) << 5)
                   | ((unsigned int)(a1.z > 0) << 6)
                   | ((unsigned int)(a1.w > 0) << 7);
    bm[(row << 8) + tid] = (unsigned char)b;
}

// ---------------- stage 1: h = x@W via MFMA (16 rows/block, 1024 blocks) ---
__global__ __launch_bounds__(256) void gat_h3(
        const float* __restrict__ x, const unsigned short* __restrict__ wt,
        const float* __restrict__ a, unsigned short* __restrict__ ht,
        float* __restrict__ f1, float* __restrict__ f2) {
    __shared__ unsigned short xs[16][264];
    __shared__ float hs[16][132];
    const int bk   = blockIdx.x;
    const int R0   = bk << 4;
    const int b    = R0 >> 11;
    const int il0  = R0 & (NN - 1);
    const int tid  = threadIdx.x;
    const int w    = tid >> 6;
    const int lane = tid & 63;
    const int m    = lane & 15;
    const int quad = lane >> 4;

#pragma unroll
    for (int rr = 0; rr < 4; ++rr) {
        const int row = (w << 2) + rr;
        float4 xv = *(const float4*)(x + (size_t)(R0 + row) * FIN + (lane << 2));
        ushort4 c4;
        c4.x = rbf(xv.x); c4.y = rbf(xv.y); c4.z = rbf(xv.z); c4.w = rbf(xv.w);
        *(ushort4*)(&xs[row][lane << 2]) = c4;
    }
    int Mlab[4], Nlab[4];
    mfma_calib(m, quad, Mlab, Nlab);
    __syncthreads();

    f32x4 zz = {0.f, 0.f, 0.f, 0.f};
    f32x4 acc[2] = {zz, zz};
#pragma unroll
    for (int kc = 0; kc < 8; ++kc) {
        const int k0 = (kc << 5) + (quad << 3);
        short8 av = *(const short8*)(&xs[m][k0]);
#pragma unroll
        for (int t = 0; t < 2; ++t) {
            const int ot = (w << 1) + t;
            short8 bw = *(const short8*)(wt + (((ot << 4) + m) << 8) + k0);
            acc[t] = __builtin_amdgcn_mfma_f32_16x16x32_bf16(av, bw, acc[t], 0, 0, 0);
        }
    }
#pragma unroll
    for (int t = 0; t < 2; ++t)
#pragma unroll
        for (int r = 0; r < 4; ++r)
            hs[Mlab[r]][(((w << 1) + t) << 4) + Nlab[r]] = acc[t][r];
    __syncthreads();

    {
        const int i   = tid >> 4;
        const int seg = tid & 15;
        const int o0  = seg << 3;
        float s1 = 0.f, s2 = 0.f;
#pragma unroll
        for (int e = 0; e < 8; ++e) {
            float hv = hs[i][o0 + e];
            s1 = fmaf(hv, a[o0 + e], s1);
            s2 = fmaf(hv, a[FOUT + o0 + e], s2);
        }
        s1 += __shfl_xor(s1, 1); s1 += __shfl_xor(s1, 2);
        s1 += __shfl_xor(s1, 4); s1 += __shfl_xor(s1, 8);
        s2 += __shfl_xor(s2, 1); s2 += __shfl_xor(s2, 2);
        s2 += __shfl_xor(s2, 4); s2 += __shfl_xor(s2, 8);
        if (seg == 0) { f1[R0 + i] = s1; f2[R0 + i] = s2; }
    }
    {
        const int o  = tid >> 1;
        const int i8 = (tid & 1) << 3;
        short8 hv;
#pragma unroll
        for (int e = 0; e < 8; ++e) hv[e] = (short)rbf(hs[i8 + e][o]);
        *(short8*)(ht + ((size_t)((b << 7) + o) << 11) + il0 + i8) = hv;
    }
}

// Software-pipeline macros for gat_s5 (named buffers, static indexing).
#define LOADC(H, MskA, MskB, Fa, Fb, c) { \
    const int j0_ = jb + ((c) << 5); \
    _Pragma("unroll") \
    for (int ot = 0; ot < 8; ++ot) \
        H[ot] = *(const short8*)(htb + ((size_t)((ot << 4) + m) << 11) + j0_); \
    MskA = bmr0[mbb + ((c) << 2)]; \
    MskB = bmr1[mbb + ((c) << 2)]; \
    Fa = *(const float4*)(f2b + j0_); \
    Fb = *(const float4*)(f2b + j0_ + 4); \
}

#define COMPC(H, MskA, MskB, Fa, Fb) { \
    float fm_[8] = {Fa.x, Fa.y, Fa.z, Fa.w, Fb.x, Fb.y, Fb.z, Fb.w}; \
    float pA_[8], pB_[8]; \
    _Pragma("unroll") \
    for (int u = 0; u < 8; ++u) { \
        float e = f1a + fm_[u]; \
        pA_[u] = (MskA & (1u << u)) ? __expf(fmaxf(e, 0.2f * e)) : 0.f; \
    } \
    _Pragma("unroll") \
    for (int u = 0; u < 8; ++u) { \
        float e = f1b + fm_[u]; \
        pB_[u] = (MskB & (1u << u)) ? __expf(fmaxf(e, 0.2f * e)) : 0.f; \
    } \
    s1 += ((pA_[0]+pA_[1])+(pA_[2]+pA_[3]))+((pA_[4]+pA_[5])+(pA_[6]+pA_[7])); \
    s2 += ((pB_[0]+pB_[1])+(pB_[2]+pB_[3]))+((pB_[4]+pB_[5])+(pB_[6]+pB_[7])); \
    short8 pf1_, pf2_; \
    _Pragma("unroll") \
    for (int u = 0; u < 8; ++u) { pf1_[u] = (short)rbf(pA_[u]); pf2_[u] = (short)rbf(pB_[u]); } \
    _Pragma("unroll") \
    for (int ot = 0; ot < 8; ++ot) { \
        acc1[ot] = __builtin_amdgcn_mfma_f32_16x16x32_bf16(pf1_, H[ot], acc1[ot], 0, 0, 0); \
        acc2[ot] = __builtin_amdgcn_mfma_f32_16x16x32_bf16(pf2_, H[ot], acc2[ot], 0, 0, 0); \
    } \
}

// ---------------- stage 2: fused masked-softmax attention ------------------
// R6 resubmit (R6 run died to infra, not kernel): R0's grid-512 direct-output
// skeleton (reg bucket caps ANY >128-reg kernel at 8 waves/CU, so R5's
// j-split bought nothing -> dropped along with fin/wsp) + bitmask loads
// (adj HBM stream gone) + explicit 2-stage software pipeline: chunk c+1's
// L2 loads issue before chunk c's ~350-cyc exp/pack/MFMA phase (T14).
// Named A/B buffers keep indexing static (rule #20).
// launch_bounds(256,2): cap 256 regs -> ~180-reg working set cannot spill.
__global__ __launch_bounds__(256, 2) void gat_s5(
        const unsigned char* __restrict__ bm, const unsigned short* __restrict__ ht,
        const float* __restrict__ f1, const float* __restrict__ f2,
        float* __restrict__ out) {
    const int bk   = blockIdx.x;        // 0..511
    const int b    = bk & 7;            // batch fastest -> per-XCD L2 locality
    const int i0   = (bk >> 3) << 5;    // 32 rows per block
    const int tid  = threadIdx.x;
    const int w    = tid >> 6;          // j-quarter
    const int lane = tid & 63;
    const int m    = lane & 15;
    const int quad = lane >> 4;

    __shared__ float accb[2][32][128];  // 32 KB
    __shared__ float sbuf[4][2][16];

    const int gi0 = (b << 11) + i0;
    const float f1a = f1[gi0 + m];
    const float f1b = f1[gi0 + 16 + m];
    const unsigned char* bmr0 = bm + ((size_t)(gi0 + m) << 8);
    const unsigned char* bmr1 = bm + ((size_t)(gi0 + 16 + m) << 8);
    const float* f2b = f2 + (b << 11);
    const unsigned short* htb = ht + ((size_t)b << 18);

    const int jb  = (w << 9) + (quad << 3);
    const int mbb = (w << 6) + quad;    // mask byte base: jb>>3

    f32x4 zz = {0.f, 0.f, 0.f, 0.f};
    f32x4 acc1[8], acc2[8];
#pragma unroll
    for (int t = 0; t < 8; ++t) { acc1[t] = zz; acc2[t] = zz; }
    float s1 = 0.f, s2 = 0.f;

    short8 hfA[8], hfB[8];
    unsigned int mA0, mB0, mA1, mB1;
    float4 faA, fbA, faB, fbB;

    // 2-stage pipeline over 16 chunks: loads for the next chunk are issued
    // before the current chunk's compute consumes its (resident) data.
    LOADC(hfA, mA0, mB0, faA, fbA, 0);
    for (int cc = 0; cc < 7; ++cc) {
        const int c0 = cc << 1;
        LOADC(hfB, mA1, mB1, faB, fbB, c0 + 1);
        COMPC(hfA, mA0, mB0, faA, fbA);
        LOADC(hfA, mA0, mB0, faA, fbA, c0 + 2);
        COMPC(hfB, mA1, mB1, faB, fbB);
    }
    LOADC(hfB, mA1, mB1, faB, fbB, 15);
    COMPC(hfA, mA0, mB0, faA, fbA);
    COMPC(hfB, mA1, mB1, faB, fbB);

    // per-row denominators (quad-reduce)
    s1 += __shfl_xor(s1, 16); s1 += __shfl_xor(s1, 32);
    s2 += __shfl_xor(s2, 16); s2 += __shfl_xor(s2, 32);
    if (lane < 16) { sbuf[w][0][lane] = s1; sbuf[w][1][lane] = s2; }

    int Mlab[4], Nlab[4];
    mfma_calib(m, quad, Mlab, Nlab);

    // 2-phase accumulator combine: waves 0,1 write; waves 2,3 add.
    if (w < 2) {
#pragma unroll
        for (int ot = 0; ot < 8; ++ot)
#pragma unroll
            for (int r = 0; r < 4; ++r) {
                accb[w][Mlab[r]][(ot << 4) + Nlab[r]]      = acc1[ot][r];
                accb[w][16 + Mlab[r]][(ot << 4) + Nlab[r]] = acc2[ot][r];
            }
    }
    __syncthreads();
    if (w >= 2) {
#pragma unroll
        for (int ot = 0; ot < 8; ++ot)
#pragma unroll
            for (int r = 0; r < 4; ++r) {
                accb[w - 2][Mlab[r]][(ot << 4) + Nlab[r]]      += acc1[ot][r];
                accb[w - 2][16 + Mlab[r]][(ot << 4) + Nlab[r]] += acc2[ot][r];
            }
    }
    __syncthreads();

    // normalize + ELU + store
    {
        const int row = tid >> 3;
        const int o0  = (tid & 7) << 4;
        const int g   = row >> 4;
        const int mm  = row & 15;
        const float s = (sbuf[0][g][mm] + sbuf[1][g][mm]) +
                        (sbuf[2][g][mm] + sbuf[3][g][mm]);
        const float inv = 1.0f / s;
        float* orow = out + (((size_t)gi0 + row) << 7) + o0;
#pragma unroll
        for (int v4 = 0; v4 < 4; ++v4) {
            float4 rv;
            float y;
            y = (accb[0][row][o0 + 4 * v4 + 0] + accb[1][row][o0 + 4 * v4 + 0]) * inv;
            rv.x = y > 0.f ? y : expm1f(y);
            y = (accb[0][row][o0 + 4 * v4 + 1] + accb[1][row][o0 + 4 * v4 + 1]) * inv;
            rv.y = y > 0.f ? y : expm1f(y);
            y = (accb[0][row][o0 + 4 * v4 + 2] + accb[1][row][o0 + 4 * v4 + 2]) * inv;
            rv.z = y > 0.f ? y : expm1f(y);
            y = (accb[0][row][o0 + 4 * v4 + 3] + accb[1][row][o0 + 4 * v4 + 3]) * inv;
            rv.w = y > 0.f ? y : expm1f(y);
            *(float4*)(orow + 4 * v4) = rv;
        }
    }
}

extern "C" void kernel_launch(void* const* d_in, const int* in_sizes, int n_in,
                              void* d_out, int out_size, void* d_ws, size_t ws_size,
                              hipStream_t stream) {
    const float* x   = nullptr;
    const int*   adj = nullptr;
    const float* W   = nullptr;
    const float* a   = nullptr;
    for (int i = 0; i < n_in; ++i) {
        const long s = in_sizes[i];
        if      (s == (long)BB * NN * NN)  adj = (const int*)d_in[i];
        else if (s == (long)BB * NN * FIN) x   = (const float*)d_in[i];
        else if (s == (long)FIN * FOUT)    W   = (const float*)d_in[i];
        else if (s == 2L * FOUT)           a   = (const float*)d_in[i];
    }
    if (!x)   x   = (const float*)d_in[0];
    if (!adj) adj = (const int*)d_in[1];
    if (!W)   W   = (const float*)d_in[2];
    if (!a)   a   = (const float*)d_in[3];
    float* out = (float*)d_out;

    unsigned short* wt = (unsigned short*)d_ws;            // 64 KB   W^T bf16
    unsigned short* ht = wt + 32768;                       // 4 MB    h^T bf16 [B][128][N]
    float* f1  = (float*)(ht + (size_t)BB * NN * FOUT);    // 64 KB
    float* f2  = f1 + BB * NN;                             // 64 KB
    unsigned char* bmw = (unsigned char*)(f2 + BB * NN);   // 4 MB    bitmask

    hipLaunchKernelGGL(gat_wt,  dim3(32),    dim3(256), 0, stream, W, wt);
    hipLaunchKernelGGL(gat_bm,  dim3(16384), dim3(256), 0, stream, adj, bmw);
    hipLaunchKernelGGL(gat_h3,  dim3(1024),  dim3(256), 0, stream, x, wt, a, ht, f1, f2);
    hipLaunchKernelGGL(gat_s5,  dim3(512),   dim3(256), 0, stream, bmw, ht, f1, f2, out);
}

// Round 8
// 239.262 us; speedup vs baseline: 1.5130x; 1.0934x over previous
//
#include <hip/hip_runtime.h>
#include <stdint.h>

#define BB   8
#define NN   2048
#define FIN  256
#define FOUT 128

using short8 = __attribute__((ext_vector_type(8))) short;
using f32x4  = __attribute__((ext_vector_type(4))) float;

__device__ __forceinline__ unsigned short rbf(float f) {
    return (unsigned short)((__float_as_uint(f) + 0x8000u) >> 16);
}

// Calibration: 2 probe MFMAs read off the true (row,col) label of each
// accumulator element (validated round 4). Epilogues index by these labels.
__device__ __forceinline__ void mfma_calib(int m, int quad, int* Mlab, int* Nlab) {
    short8 pa1, pb1, pa2, pb2;
    const short one = (short)0x3F80;            // bf16 1.0
    const short mb  = (short)rbf((float)m);     // bf16 m (exact, m<16)
#pragma unroll
    for (int j = 0; j < 8; ++j) { pa1[j] = 0; pa2[j] = 0; pb1[j] = mb; pb2[j] = one; }
    if (quad == 0) { pa1[0] = one; pa2[0] = mb; }
    f32x4 zz = {0.f, 0.f, 0.f, 0.f};
    f32x4 c1 = __builtin_amdgcn_mfma_f32_16x16x32_bf16(pa1, pb1, zz, 0, 0, 0);
    f32x4 c2 = __builtin_amdgcn_mfma_f32_16x16x32_bf16(pa2, pb2, zz, 0, 0, 0);
#pragma unroll
    for (int r = 0; r < 4; ++r) {
        Nlab[r] = ((int)c1[r]) & 15;
        Mlab[r] = ((int)c2[r]) & 15;
    }
}

// ---------------- W[256][128] fp32 -> wt[128][256] bf16 (W^T) --------------
__global__ __launch_bounds__(256) void gat_wt(const float* __restrict__ W,
                                              unsigned short* __restrict__ wt) {
    const int g  = blockIdx.x * 256 + threadIdx.x;
    const int k  = g >> 5;
    const int o4 = (g & 31) << 2;
    float4 wv = *(const float4*)(W + (k << 7) + o4);
    wt[((o4 + 0) << 8) + k] = rbf(wv.x);
    wt[((o4 + 1) << 8) + k] = rbf(wv.y);
    wt[((o4 + 2) << 8) + k] = rbf(wv.z);
    wt[((o4 + 3) << 8) + k] = rbf(wv.w);
}

// ---------------- adj -> bm2: wave-tiled bitmask --------------------------
// bm2 byte index: [i>>5][c][w][quad][i&31]  (8192 B per 32-row group).
// The 32 bytes a wave needs per (chunk, w, quad) sit in one 128 B window.
__global__ __launch_bounds__(256) void gat_bm2(const int* __restrict__ adj,
                                               unsigned char* __restrict__ bm) {
    const int row = blockIdx.x;                 // 0..16383 (attention row i)
    const int tid = threadIdx.x;                // byte col over j: 0..255
    const int4* p = (const int4*)(adj + ((size_t)row << 11) + (tid << 3));
    int4 a0 = p[0];
    int4 a1 = p[1];
    unsigned int b = (unsigned int)(a0.x > 0)
                   | ((unsigned int)(a0.y > 0) << 1)
                   | ((unsigned int)(a0.z > 0) << 2)
                   | ((unsigned int)(a0.w > 0) << 3)
                   | ((unsigned int)(a1.x > 0) << 4)
                   | ((unsigned int)(a1.y > 0) << 5)
                   | ((unsigned int)(a1.z > 0) << 6)
                   | ((unsigned int)(a1.w > 0) << 7);
    const int w = tid >> 6, c = (tid >> 2) & 15, q = tid & 3;
    bm[((size_t)(row >> 5) << 13) + (c << 9) + (w << 7) + (q << 5) + (row & 31)]
        = (unsigned char)b;
}

// ---------------- stage 1: h = x@W via MFMA; ht2 in wave-tiled layout -----
// ht2 short index: ((((b*4+w)*16+c)*8+ot)*512) + (quad*16+m)*8 + e
// so that gat_s6's (c,ot) load is base + lane*16B -> ONE coalesced 1 KB txn.
__global__ __launch_bounds__(256) void gat_h4(
        const float* __restrict__ x, const unsigned short* __restrict__ wt,
        const float* __restrict__ a, unsigned short* __restrict__ ht,
        float* __restrict__ f1, float* __restrict__ f2) {
    __shared__ unsigned short xs[16][264];
    __shared__ float hs[16][132];
    const int bk   = blockIdx.x;
    const int R0   = bk << 4;
    const int b    = R0 >> 11;
    const int il0  = R0 & (NN - 1);
    const int tid  = threadIdx.x;
    const int w    = tid >> 6;
    const int lane = tid & 63;
    const int m    = lane & 15;
    const int quad = lane >> 4;

#pragma unroll
    for (int rr = 0; rr < 4; ++rr) {
        const int row = (w << 2) + rr;
        float4 xv = *(const float4*)(x + (size_t)(R0 + row) * FIN + (lane << 2));
        ushort4 c4;
        c4.x = rbf(xv.x); c4.y = rbf(xv.y); c4.z = rbf(xv.z); c4.w = rbf(xv.w);
        *(ushort4*)(&xs[row][lane << 2]) = c4;
    }
    int Mlab[4], Nlab[4];
    mfma_calib(m, quad, Mlab, Nlab);
    __syncthreads();

    f32x4 zz = {0.f, 0.f, 0.f, 0.f};
    f32x4 acc[2] = {zz, zz};
#pragma unroll
    for (int kc = 0; kc < 8; ++kc) {
        const int k0 = (kc << 5) + (quad << 3);
        short8 av = *(const short8*)(&xs[m][k0]);
#pragma unroll
        for (int t = 0; t < 2; ++t) {
            const int ot = (w << 1) + t;
            short8 bw = *(const short8*)(wt + (((ot << 4) + m) << 8) + k0);
            acc[t] = __builtin_amdgcn_mfma_f32_16x16x32_bf16(av, bw, acc[t], 0, 0, 0);
        }
    }
#pragma unroll
    for (int t = 0; t < 2; ++t)
#pragma unroll
        for (int r = 0; r < 4; ++r)
            hs[Mlab[r]][(((w << 1) + t) << 4) + Nlab[r]] = acc[t][r];
    __syncthreads();

    {
        const int i   = tid >> 4;
        const int seg = tid & 15;
        const int o0  = seg << 3;
        float s1 = 0.f, s2 = 0.f;
#pragma unroll
        for (int e = 0; e < 8; ++e) {
            float hv = hs[i][o0 + e];
            s1 = fmaf(hv, a[o0 + e], s1);
            s2 = fmaf(hv, a[FOUT + o0 + e], s2);
        }
        s1 += __shfl_xor(s1, 1); s1 += __shfl_xor(s1, 2);
        s1 += __shfl_xor(s1, 4); s1 += __shfl_xor(s1, 8);
        s2 += __shfl_xor(s2, 1); s2 += __shfl_xor(s2, 2);
        s2 += __shfl_xor(s2, 4); s2 += __shfl_xor(s2, 8);
        if (seg == 0) { f1[R0 + i] = s1; f2[R0 + i] = s2; }
    }
    {
        const int o  = tid >> 1;            // 0..127
        const int i8 = (tid & 1) << 3;      // 0 or 8
        const int jj = il0 + i8;            // multiple of 8
        const int wj = jj >> 9;
        const int cj = (jj >> 5) & 15;
        const int qj = (jj >> 3) & 3;
        short8 hv;
#pragma unroll
        for (int e = 0; e < 8; ++e) hv[e] = (short)rbf(hs[i8 + e][o]);
        const size_t addr = ((size_t)b << 18) + ((size_t)wj << 16) + (cj << 12)
                          + ((o >> 4) << 9) + (((qj << 4) + (o & 15)) << 3);
        *(short8*)(ht + addr) = hv;
    }
}

// Software-pipeline macros for gat_s6 (named buffers, static indexing).
// ht2 load for (c,ot): base + lane*16B  -> fully coalesced.
// mask load: 2 bytes from a 128 B window shared by the wave.
#define LOADC(H, MskA, MskB, Fa, Fb, c) { \
    const unsigned short* hp_ = htb + ((c) << 12); \
    _Pragma("unroll") \
    for (int ot = 0; ot < 8; ++ot) \
        H[ot] = *(const short8*)(hp_ + (ot << 9) + (lane << 3)); \
    MskA = bmb[((c) << 9) + mq]; \
    MskB = bmb[((c) << 9) + mq + 16]; \
    const int j0_ = jb + ((c) << 5); \
    Fa = *(const float4*)(f2b + j0_); \
    Fb = *(const float4*)(f2b + j0_ + 4); \
}

#define COMPC(H, MskA, MskB, Fa, Fb) { \
    float fm_[8] = {Fa.x, Fa.y, Fa.z, Fa.w, Fb.x, Fb.y, Fb.z, Fb.w}; \
    float pA_[8], pB_[8]; \
    _Pragma("unroll") \
    for (int u = 0; u < 8; ++u) { \
        float e = f1a + fm_[u]; \
        pA_[u] = (MskA & (1u << u)) ? __expf(fmaxf(e, 0.2f * e)) : 0.f; \
    } \
    _Pragma("unroll") \
    for (int u = 0; u < 8; ++u) { \
        float e = f1b + fm_[u]; \
        pB_[u] = (MskB & (1u << u)) ? __expf(fmaxf(e, 0.2f * e)) : 0.f; \
    } \
    s1 += ((pA_[0]+pA_[1])+(pA_[2]+pA_[3]))+((pA_[4]+pA_[5])+(pA_[6]+pA_[7])); \
    s2 += ((pB_[0]+pB_[1])+(pB_[2]+pB_[3]))+((pB_[4]+pB_[5])+(pB_[6]+pB_[7])); \
    short8 pf1_, pf2_; \
    _Pragma("unroll") \
    for (int u = 0; u < 8; ++u) { pf1_[u] = (short)rbf(pA_[u]); pf2_[u] = (short)rbf(pB_[u]); } \
    _Pragma("unroll") \
    for (int ot = 0; ot < 8; ++ot) { \
        acc1[ot] = __builtin_amdgcn_mfma_f32_16x16x32_bf16(pf1_, H[ot], acc1[ot], 0, 0, 0); \
        acc2[ot] = __builtin_amdgcn_mfma_f32_16x16x32_bf16(pf2_, H[ot], acc2[ot], 0, 0, 0); \
    } \
}

// ---------------- stage 2: fused masked-softmax attention ------------------
// R8: R7 skeleton with COALESCED inner-loop loads. R7 disproved the "load
// latency per se" theory (explicit pipeline = no change); the remaining
// suspect is scatter cost: the old ht layout made every hf load 16 segments
// 4 KB apart (16 TA transactions/instr). ht2/bm2 are permuted so each load
// is one contiguous transaction. Loop math, registers, epilogue unchanged.
__global__ __launch_bounds__(256, 2) void gat_s6(
        const unsigned char* __restrict__ bm, const unsigned short* __restrict__ ht,
        const float* __restrict__ f1, const float* __restrict__ f2,
        float* __restrict__ out) {
    const int bk   = blockIdx.x;        // 0..511
    const int b    = bk & 7;            // batch fastest -> per-XCD L2 locality
    const int i0   = (bk >> 3) << 5;    // 32 rows per block
    const int tid  = threadIdx.x;
    const int w    = tid >> 6;          // j-quarter
    const int lane = tid & 63;
    const int m    = lane & 15;
    const int quad = lane >> 4;

    __shared__ float accb[2][32][128];  // 32 KB
    __shared__ float sbuf[4][2][16];

    const int gi0 = (b << 11) + i0;
    const float f1a = f1[gi0 + m];
    const float f1b = f1[gi0 + 16 + m];
    const unsigned char* bmb = bm + ((size_t)gi0 << 8);
    const int mq = (w << 7) + (quad << 5) + m;
    const float* f2b = f2 + (b << 11);
    const unsigned short* htb = ht + ((size_t)b << 18) + ((size_t)w << 16);

    const int jb  = (w << 9) + (quad << 3);

    f32x4 zz = {0.f, 0.f, 0.f, 0.f};
    f32x4 acc1[8], acc2[8];
#pragma unroll
    for (int t = 0; t < 8; ++t) { acc1[t] = zz; acc2[t] = zz; }
    float s1 = 0.f, s2 = 0.f;

    short8 hfA[8], hfB[8];
    unsigned int mA0, mB0, mA1, mB1;
    float4 faA, fbA, faB, fbB;

    // 2-stage pipeline over 16 chunks.
    LOADC(hfA, mA0, mB0, faA, fbA, 0);
    for (int cc = 0; cc < 7; ++cc) {
        const int c0 = cc << 1;
        LOADC(hfB, mA1, mB1, faB, fbB, c0 + 1);
        COMPC(hfA, mA0, mB0, faA, fbA);
        LOADC(hfA, mA0, mB0, faA, fbA, c0 + 2);
        COMPC(hfB, mA1, mB1, faB, fbB);
    }
    LOADC(hfB, mA1, mB1, faB, fbB, 15);
    COMPC(hfA, mA0, mB0, faA, fbA);
    COMPC(hfB, mA1, mB1, faB, fbB);

    // per-row denominators (quad-reduce)
    s1 += __shfl_xor(s1, 16); s1 += __shfl_xor(s1, 32);
    s2 += __shfl_xor(s2, 16); s2 += __shfl_xor(s2, 32);
    if (lane < 16) { sbuf[w][0][lane] = s1; sbuf[w][1][lane] = s2; }

    int Mlab[4], Nlab[4];
    mfma_calib(m, quad, Mlab, Nlab);

    // 2-phase accumulator combine: waves 0,1 write; waves 2,3 add.
    if (w < 2) {
#pragma unroll
        for (int ot = 0; ot < 8; ++ot)
#pragma unroll
            for (int r = 0; r < 4; ++r) {
                accb[w][Mlab[r]][(ot << 4) + Nlab[r]]      = acc1[ot][r];
                accb[w][16 + Mlab[r]][(ot << 4) + Nlab[r]] = acc2[ot][r];
            }
    }
    __syncthreads();
    if (w >= 2) {
#pragma unroll
        for (int ot = 0; ot < 8; ++ot)
#pragma unroll
            for (int r = 0; r < 4; ++r) {
                accb[w - 2][Mlab[r]][(ot << 4) + Nlab[r]]      += acc1[ot][r];
                accb[w - 2][16 + Mlab[r]][(ot << 4) + Nlab[r]] += acc2[ot][r];
            }
    }
    __syncthreads();

    // normalize + ELU + store
    {
        const int row = tid >> 3;
        const int o0  = (tid & 7) << 4;
        const int g   = row >> 4;
        const int mm  = row & 15;
        const float s = (sbuf[0][g][mm] + sbuf[1][g][mm]) +
                        (sbuf[2][g][mm] + sbuf[3][g][mm]);
        const float inv = 1.0f / s;
        float* orow = out + (((size_t)gi0 + row) << 7) + o0;
#pragma unroll
        for (int v4 = 0; v4 < 4; ++v4) {
            float4 rv;
            float y;
            y = (accb[0][row][o0 + 4 * v4 + 0] + accb[1][row][o0 + 4 * v4 + 0]) * inv;
            rv.x = y > 0.f ? y : expm1f(y);
            y = (accb[0][row][o0 + 4 * v4 + 1] + accb[1][row][o0 + 4 * v4 + 1]) * inv;
            rv.y = y > 0.f ? y : expm1f(y);
            y = (accb[0][row][o0 + 4 * v4 + 2] + accb[1][row][o0 + 4 * v4 + 2]) * inv;
            rv.z = y > 0.f ? y : expm1f(y);
            y = (accb[0][row][o0 + 4 * v4 + 3] + accb[1][row][o0 + 4 * v4 + 3]) * inv;
            rv.w = y > 0.f ? y : expm1f(y);
            *(float4*)(orow + 4 * v4) = rv;
        }
    }
}

extern "C" void kernel_launch(void* const* d_in, const int* in_sizes, int n_in,
                              void* d_out, int out_size, void* d_ws, size_t ws_size,
                              hipStream_t stream) {
    const float* x   = nullptr;
    const int*   adj = nullptr;
    const float* W   = nullptr;
    const float* a   = nullptr;
    for (int i = 0; i < n_in; ++i) {
        const long s = in_sizes[i];
        if      (s == (long)BB * NN * NN)  adj = (const int*)d_in[i];
        else if (s == (long)BB * NN * FIN) x   = (const float*)d_in[i];
        else if (s == (long)FIN * FOUT)    W   = (const float*)d_in[i];
        else if (s == 2L * FOUT)           a   = (const float*)d_in[i];
    }
    if (!x)   x   = (const float*)d_in[0];
    if (!adj) adj = (const int*)d_in[1];
    if (!W)   W   = (const float*)d_in[2];
    if (!a)   a   = (const float*)d_in[3];
    float* out = (float*)d_out;

    unsigned short* wt = (unsigned short*)d_ws;            // 64 KB   W^T bf16
    unsigned short* ht = wt + 32768;                       // 4 MB    ht2 wave-tiled
    float* f1  = (float*)(ht + (size_t)BB * NN * FOUT);    // 64 KB
    float* f2  = f1 + BB * NN;                             // 64 KB
    unsigned char* bmw = (unsigned char*)(f2 + BB * NN);   // 4 MB    bm2 wave-tiled

    hipLaunchKernelGGL(gat_wt,  dim3(32),    dim3(256), 0, stream, W, wt);
    hipLaunchKernelGGL(gat_bm2, dim3(16384), dim3(256), 0, stream, adj, bmw);
    hipLaunchKernelGGL(gat_h4,  dim3(1024),  dim3(256), 0, stream, x, wt, a, ht, f1, f2);
    hipLaunchKernelGGL(gat_s6,  dim3(512),   dim3(256), 0, stream, bmw, ht, f1, f2, out);
}